// Round 5
// baseline (456.194 us; speedup 1.0000x reference)
//
#include <hip/hip_runtime.h>
#include <hip/hip_bf16.h>

#define BB 8
#define CC 256
#define HH 128
#define WW 128

typedef __attribute__((ext_vector_type(8))) short bf16x8;
typedef __attribute__((ext_vector_type(4))) float f32x4;

// fp32 -> bf16 round-to-nearest-even
static __device__ __forceinline__ unsigned short f2bf(float f) {
  unsigned int u = __builtin_bit_cast(unsigned int, f);
  u += 0x7fffu + ((u >> 16) & 1u);
  return (unsigned short)(u >> 16);
}

// async 16B global->LDS; LDS dest = wave-uniform base + lane*16
static __device__ __forceinline__ void async16(const void* g, void* l) {
#if __has_builtin(__builtin_amdgcn_global_load_lds)
  __builtin_amdgcn_global_load_lds(
      (__attribute__((address_space(1))) void*)(unsigned long long)(g),
      (__attribute__((address_space(3))) void*)(unsigned int)(unsigned long long)(l),
      16, 0, 0);
#else
  *(bf16x8*)l = *(const bf16x8*)g;
#endif
}

// ---------------------------------------------------------------------------
// Kernel 1 (merged): blocks 0..4095 = transpose_x, blocks 4096..4127 =
// convert_w. Both paths byte-identical to the round-4 kernels; merged to cut
// one launch + its gap. Shared-mem union 36 KB (4 blocks/CU either path).
// ---------------------------------------------------------------------------
__global__ __launch_bounds__(256) void k_pre(const float* __restrict__ x,
                                             const float* __restrict__ w,
                                             unsigned short* __restrict__ Xc,
                                             unsigned short* __restrict__ Wt,
                                             float* __restrict__ pS,
                                             float* __restrict__ pC0,
                                             float* __restrict__ pC1) {
  __shared__ __align__(16) unsigned char smem[36864];
  const int t = threadIdx.x;
  const int bx = blockIdx.x;

  if (bx >= 4096) {
    // ---- convert_w: w [co][ci][3][3] fp32 -> Wt2 [tap][ci_oct][co][8] bf16
    unsigned short* lw = (unsigned short*)smem;  // [cl][ci][tap]
    const int co0 = (bx - 4096) << 3;
    const float* src = w + co0 * 2304;
    for (int k = t; k < 18432; k += 256) lw[k] = f2bf(src[k]);  // coalesced
    __syncthreads();
    for (int g = t; g < 18432; g += 256) {
      const int tap = g >> 11, rem = g & 2047;
      const int o = rem >> 6, rem2 = rem & 63;
      const int cl = rem2 >> 3, e = rem2 & 7;
      Wt[(((tap << 5) + o) << 11) + ((co0 + cl) << 3) + e] =
          lw[cl * 2304 + ((o << 3) + e) * 9 + tap];
    }
    return;
  }

  // ---- transpose_x: x [b][c][h][w] fp32 -> Xc2 [b][h][ci_oct][w][8] bf16,
  // plus per-(b,h) pool partials (no atomics)
  float (*tile)[130] = (float(*)[130])smem;
  const int bh = bx >> 2;              // 0..1023 = b*128 + h
  const int b = bh >> 7;
  const int c0 = (bx & 3) << 6;        // 0,64,128,192
  const float* xp = x + ((b * CC) * HH + (bh & 127)) * WW;
#pragma unroll
  for (int i = 0; i < 8; ++i) {
    int idx = t + (i << 8);            // 0..2047
    int cr = idx >> 5, wq = idx & 31;  // 32 float4 per 128-wide row
    float4 v = *(const float4*)(xp + (c0 + cr) * (HH * WW) + (wq << 2));
    tile[cr][(wq << 2) + 0] = v.x;
    tile[cr][(wq << 2) + 1] = v.y;
    tile[cr][(wq << 2) + 2] = v.z;
    tile[cr][(wq << 2) + 3] = v.w;
  }
  __syncthreads();
  const int ob = c0 >> 3;
#pragma unroll
  for (int i = 0; i < 4; ++i) {
    int g = t + (i << 8);              // 0..1023
    int o = g >> 7, wr = g & 127;
    bf16x8 v;
#pragma unroll
    for (int e = 0; e < 8; ++e) v[e] = (short)f2bf(tile[(o << 3) + e][wr]);
    *(bf16x8*)(Xc + ((bh * 32) + ob + o) * 1024 + wr * 8) = v;
  }
  {
    const int c = t >> 2, seg = t & 3;
    float s = 0.f;
#pragma unroll
    for (int k = 0; k < 32; ++k)
      s += tile[c][(seg << 5) + ((k + (seg << 3)) & 31)];  // bank-phase rotate
    s += __shfl_xor(s, 1);
    s += __shfl_xor(s, 2);
    if (seg == 0) {
      const int idx = (bh << 8) + c0 + c;
      pS[idx]  = s;
      pC0[idx] = tile[c][0];
      pC1[idx] = tile[c][127];
    }
  }
}

// ---------------------------------------------------------------------------
// Kernel 2: p[b][co] = bd[co] + (1/16384) * sum_k w[co][k] * ts[b][k].
// Channel sums reduced from the per-(b,h) partials (unchanged from round 4).
// ---------------------------------------------------------------------------
__global__ __launch_bounds__(256) void k_pool2(const float* __restrict__ w,
                                               const float* __restrict__ bd,
                                               const float* __restrict__ pS,
                                               const float* __restrict__ pC0,
                                               const float* __restrict__ pC1,
                                               float* __restrict__ p_buf) {
  __shared__ float ts[2304];   // flat [ci*9 + tap]
  const int b = blockIdx.y, t = threadIdx.x;
  const int lane = t & 63, wid = t >> 6;
  {
    const int base = (b << 15) + t;          // b*128*256 + ci
    float S = 0.f, C0 = 0.f, C1 = 0.f;
#pragma unroll 4
    for (int h = 0; h < 128; ++h) {
      S  += pS [base + (h << 8)];
      C0 += pC0[base + (h << 8)];
      C1 += pC1[base + (h << 8)];
    }
    const float R0 = pS[base],  R1 = pS[base + (127 << 8)];
    const float x00 = pC0[base], xH0 = pC0[base + (127 << 8)];
    const float x0W = pC1[base], xHW = pC1[base + (127 << 8)];
    const float er[3] = {R1, 0.f, R0};
    const float ec[3] = {C1, 0.f, C0};
    const float cor[9] = {xHW, 0.f, xH0, 0.f, 0.f, 0.f, x0W, 0.f, x00};
#pragma unroll
    for (int kh = 0; kh < 3; ++kh)
#pragma unroll
      for (int kw = 0; kw < 3; ++kw)
        ts[t * 9 + kh * 3 + kw] = S - er[kh] - ec[kw] + cor[kh * 3 + kw];
  }
  __syncthreads();
  float4 tv[9];
#pragma unroll
  for (int q = 0; q < 9; ++q) tv[q] = *(const float4*)&ts[(q * 64 + lane) * 4];
  const int co = (blockIdx.x << 3) + (wid << 1);
#pragma unroll
  for (int c2 = 0; c2 < 2; ++c2) {
    const float4* wr = (const float4*)(w + (co + c2) * 2304) + lane;
    float s = 0.f;
#pragma unroll
    for (int q = 0; q < 9; ++q) {
      float4 wv = wr[q * 64];
      s += wv.x * tv[q].x + wv.y * tv[q].y + wv.z * tv[q].z + wv.w * tv[q].w;
    }
    s += __shfl_xor(s, 1);  s += __shfl_xor(s, 2);  s += __shfl_xor(s, 4);
    s += __shfl_xor(s, 8);  s += __shfl_xor(s, 16); s += __shfl_xor(s, 32);
    if (lane == 0) p_buf[(b << 8) + co + c2] = bd[co + c2] + s * (1.0f / 16384.0f);
  }
}

// ---------------------------------------------------------------------------
// Kernel 3 v6: implicit-GEMM conv + fused SE MLP prologue.
//  - prologue: h1 = relu(w1@p+b1) and this block's 128-co scale slice,
//    computed into LDS (same math/order as old k_se2) -> k_se2 launch gone.
//  - staging moved from loop-top to step s==8: vmcnt is issue-ordered, so
//    with staging issued AFTER the last A-prefetch (s<=7), no A-consume
//    drains the 16 staging loads; only the end barrier waits ~230cyc
//    (vs ~600cyc s=0 stall). Zero register delta vs v5 (af[3], bg[2]).
//  - s_setprio(1/0) around MFMA clusters kept from v5.
// ---------------------------------------------------------------------------
__global__ __launch_bounds__(256, 2) void k_conv(
    const unsigned short* __restrict__ Xc, const unsigned short* __restrict__ Wt,
    const float* __restrict__ bias, const float* __restrict__ p_buf,
    const float* __restrict__ w1, const float* __restrict__ b1,
    const float* __restrict__ w2, const float* __restrict__ b2,
    float* __restrict__ out) {
  // dynamic LDS: Xs [buf:2][dh:4][oct:4][wp:130][8] bf16 = 66560 B,
  // then p_lds[256] + h1[64] + sc[128] floats = 1792 B. Total 68352 B.
  extern __shared__ __align__(16) unsigned short Xs[];
  float* p_lds = (float*)(Xs + 33280);
  float* h1s   = p_lds + 256;
  float* sc    = h1s + 64;
  const int t = threadIdx.x;
  const int lin = (blockIdx.y << 1) | blockIdx.x;   // 0..1023
  const int Wk = ((lin & 7) << 7) | (lin >> 3);     // XCD swizzle: XCD k -> b=k
  const int m0 = (Wk & 1) << 7;
  const int bhp = Wk >> 1;                          // 0..511
  const int b = bhp >> 6;
  const int h0 = (bhp & 63) << 1;                   // even row; block does h0,h0+1
  const int lane = t & 63, wid = t >> 6;
  const int wave_m = (wid & 1) << 6, wave_n = (wid >> 1) << 6;
  const int n0 = lane & 15, quad = lane >> 4;
  const int part = wid & 1, rsel = wid >> 1;

  bf16x8 z8 = {0, 0, 0, 0, 0, 0, 0, 0};
  // zero halo columns wp=0 and wp=129 (both buffers), once
  if (t < 64) {
    int bi = t >> 5, rem = t & 31;
    int dh = rem >> 3, rem2 = rem & 7, q = rem2 >> 1, side = rem2 & 1;
    *(bf16x8*)&Xs[bi * 16640 + dh * 4160 + q * 1040 + (side ? 1032 : 0)] = z8;
  }
  // out-of-image rows stay zero (staging skips them)
  if (h0 == 0 || h0 == 126) {
    const int dhz = (h0 == 0) ? 0 : 3;
    for (int g = t; g < 1040; g += 256) {
      int bi = g >= 520, gg = g - bi * 520;
      *(bf16x8*)&Xs[bi * 16640 + dhz * 4160 + gg * 8] = z8;
    }
  }

  auto stage = [&](int cb8, int bi) {
    const int ob = cb8 << 2;
#pragma unroll
    for (int r = 0; r < 8; ++r) {
      const int rr = (r << 1) | rsel;      // 16 regions of 2 KB: (dh, octet)
      const int dh = rr >> 2, q = rr & 3;
      const int hh = h0 - 1 + dh;
      if (hh >= 0 && hh < HH) {
        const unsigned short* gp =
            Xc + ((((b << 7) + hh) * 32 + ob + q) << 10) + (part << 9) + (lane << 3);
        unsigned short* lp =
            &Xs[bi * 16640 + dh * 4160 + q * 1040 + 8 + (part << 9) + (lane << 3)];
        async16(gp, lp);
      }
    }
  };

  f32x4 acc[2][4][4];
  f32x4 zero4 = {0.f, 0.f, 0.f, 0.f};
#pragma unroll
  for (int r = 0; r < 2; ++r)
#pragma unroll
    for (int i = 0; i < 4; ++i)
#pragma unroll
      for (int j = 0; j < 4; ++j) acc[r][i][j] = zero4;

  stage(0, 0);

  // ---- fused SE MLP (overlaps stage(0) latency); identical math to k_se2
  p_lds[t] = p_buf[(b << 8) + t];
  __syncthreads();
  {
    const float4 pv = *(const float4*)&p_lds[lane << 2];
#pragma unroll
    for (int i = 0; i < 16; ++i) {
      const int r = (wid << 4) + i;
      float4 wv = ((const float4*)(w1 + (r << 8)))[lane];
      float s = wv.x * pv.x + wv.y * pv.y + wv.z * pv.z + wv.w * pv.w;
      s += __shfl_xor(s, 1);  s += __shfl_xor(s, 2);  s += __shfl_xor(s, 4);
      s += __shfl_xor(s, 8);  s += __shfl_xor(s, 16); s += __shfl_xor(s, 32);
      if (lane == 0) {
        float v = b1[r] + s;
        h1s[r] = v > 0.f ? v : 0.f;
      }
    }
  }
  __syncthreads();
  if (t < 128) {
    float s2 = b2[m0 + t];
    const float* wr2 = w2 + ((m0 + t) << 6);
#pragma unroll
    for (int k = 0; k < 64; ++k) s2 += wr2[k] * h1s[k];
    sc[t] = 1.0f / (1.0f + expf(-s2));
  }
  __syncthreads();

  for (int cb8 = 0; cb8 < 8; ++cb8) {
    const int cur = cb8 & 1;
    // A base: Wt2[tap][(cb8*4)+quad][co][8]; B base in current Xs buffer
    const unsigned short* wb =
        Wt + ((((cb8 << 2) + quad) << 8) + m0 + wave_m + n0) * 8;
    const unsigned short* xb = &Xs[cur * 16640 + quad * 1040 + (wave_n + n0) * 8];

    // A plane p = kw*3+kh -> Wt tap = kh*3+kw = (p%3)*3 + p/3 ; slot p%3.
    bf16x8 af[3][4], bg[2][4];
#pragma unroll
    for (int i = 0; i < 4; ++i) af[0][i] = *(const bf16x8*)(wb + 0 * 65536 + i * 128);
#pragma unroll
    for (int i = 0; i < 4; ++i) af[1][i] = *(const bf16x8*)(wb + 3 * 65536 + i * 128);
#pragma unroll
    for (int j = 0; j < 4; ++j) bg[0][j] = *(const bf16x8*)(xb + (j << 4) * 8);

#pragma unroll
    for (int kw = 0; kw < 3; ++kw) {
#pragma unroll
      for (int dh = 0; dh < 4; ++dh) {
        const int s = (kw << 2) + dh;          // 12 steps per cb8
        if (s < 11) {                           // B prefetch, 1 step ahead
          const int sn = s + 1, kwn = sn >> 2, dhn = sn & 3;
#pragma unroll
          for (int j = 0; j < 4; ++j)
            bg[sn & 1][j] =
                *(const bf16x8*)(xb + dhn * 4160 + (((j << 4) + kwn)) * 8);
        }
        if (s == 8 && cb8 < 7) stage(cb8 + 1, cur ^ 1);  // after last A-prefetch
        __builtin_amdgcn_s_setprio(1);
        if (dh >= 1) {                          // row1: plane p1 = kw*3+dh-1
          const int p1 = kw * 3 + dh - 1;
#pragma unroll
          for (int i = 0; i < 4; ++i)
#pragma unroll
            for (int j = 0; j < 4; ++j)
              acc[1][i][j] = __builtin_amdgcn_mfma_f32_16x16x32_bf16(
                  af[p1 % 3][i], bg[s & 1][j], acc[1][i][j], 0, 0, 0);
        }
        if (dh <= 2) {                          // row0: plane p0 = kw*3+dh
          const int p0 = kw * 3 + dh;
#pragma unroll
          for (int i = 0; i < 4; ++i)
#pragma unroll
            for (int j = 0; j < 4; ++j)
              acc[0][i][j] = __builtin_amdgcn_mfma_f32_16x16x32_bf16(
                  af[p0 % 3][i], bg[s & 1][j], acc[0][i][j], 0, 0, 0);
        }
        __builtin_amdgcn_s_setprio(0);
        if (s >= 1 && s <= 7) {                 // A prefetch: plane s+1
          const int pn = s + 1;                  // tap = (pn%3)*3 + pn/3
          const int tapn = (pn % 3) * 3 + pn / 3;
#pragma unroll
          for (int i = 0; i < 4; ++i)
            af[pn % 3][i] = *(const bf16x8*)(wb + tapn * 65536 + i * 128);
        }
      }
    }
    __syncthreads();
  }

  // epilogue: D col = lane&15 (w), row = quad*4+reg (co); y = (acc+bias)*scale
#pragma unroll
  for (int i = 0; i < 4; ++i) {
    const int mloc = wave_m + (i << 4) + (quad << 2);  // 0..127 within block
    const int mrow = m0 + mloc;
    float bs[4], ss[4];
#pragma unroll
    for (int r4 = 0; r4 < 4; ++r4) {
      bs[r4] = bias[mrow + r4];
      ss[r4] = sc[mloc + r4];
    }
#pragma unroll
    for (int r = 0; r < 2; ++r)
#pragma unroll
      for (int j = 0; j < 4; ++j) {
        const int wcol = wave_n + (j << 4) + n0;
        float* op = out + ((((b << 8) + mrow) * HH) + h0 + r) * WW + wcol;
#pragma unroll
        for (int r4 = 0; r4 < 4; ++r4)
          op[r4 * (HH * WW)] = (acc[r][i][j][r4] + bs[r4]) * ss[r4];
      }
  }
}

extern "C" void kernel_launch(void* const* d_in, const int* in_sizes, int n_in,
                              void* d_out, int out_size, void* d_ws, size_t ws_size,
                              hipStream_t stream) {
  const float* x  = (const float*)d_in[0];
  const float* wd = (const float*)d_in[1];
  const float* bd = (const float*)d_in[2];
  const float* w1 = (const float*)d_in[3];
  const float* b1 = (const float*)d_in[4];
  const float* w2 = (const float*)d_in[5];
  const float* b2 = (const float*)d_in[6];
  float* out = (float*)d_out;

  // workspace layout
  char* ws = (char*)d_ws;
  unsigned short* Xc = (unsigned short*)ws;                     // 67108864 B
  unsigned short* Wt = (unsigned short*)(ws + 67108864);        //  1179648 B
  float* p_buf = (float*)(ws + 68362240);                       //     8192 B

  // per-(b,h) pool partials live in d_out scratch (dead until k_conv writes):
  // pS/pC0/pC1 each 8*128*256 floats = 1 MB
  float* pS  = out;
  float* pC0 = out + 262144;
  float* pC1 = out + 524288;

  // k_conv uses 68,352 B dynamic LDS (> 64 KB static limit)
  (void)hipFuncSetAttribute((const void*)k_conv,
                            hipFuncAttributeMaxDynamicSharedMemorySize, 68352);

  k_pre<<<dim3(4128), dim3(256), 0, stream>>>(x, wd, Xc, Wt, pS, pC0, pC1);
  k_pool2<<<dim3(32, 8), dim3(256), 0, stream>>>(wd, bd, pS, pC0, pC1, p_buf);
  k_conv<<<dim3(2, 512), dim3(256), 68352, stream>>>(Xc, Wt, bd, p_buf,
                                                     w1, b1, w2, b2, out);
}

// Round 6
// 378.928 us; speedup vs baseline: 1.2039x; 1.2039x over previous
//
#include <hip/hip_runtime.h>
#include <hip/hip_bf16.h>

#define BB 8
#define CC 256
#define HH 128
#define WW 128

typedef __attribute__((ext_vector_type(8))) short bf16x8;
typedef __attribute__((ext_vector_type(4))) float f32x4;

// fp32 -> bf16 round-to-nearest-even
static __device__ __forceinline__ unsigned short f2bf(float f) {
  unsigned int u = __builtin_bit_cast(unsigned int, f);
  u += 0x7fffu + ((u >> 16) & 1u);
  return (unsigned short)(u >> 16);
}

// async 16B global->LDS; LDS dest = wave-uniform base + lane*16
static __device__ __forceinline__ void async16(const void* g, void* l) {
#if __has_builtin(__builtin_amdgcn_global_load_lds)
  __builtin_amdgcn_global_load_lds(
      (__attribute__((address_space(1))) void*)(unsigned long long)(g),
      (__attribute__((address_space(3))) void*)(unsigned int)(unsigned long long)(l),
      16, 0, 0);
#else
  *(bf16x8*)l = *(const bf16x8*)g;
#endif
}

// ---------------------------------------------------------------------------
// Kernel 1 (merged): blocks 0..4095 = transpose_x, blocks 4096..4127 =
// convert_w. Unchanged from round 5.
// ---------------------------------------------------------------------------
__global__ __launch_bounds__(256) void k_pre(const float* __restrict__ x,
                                             const float* __restrict__ w,
                                             unsigned short* __restrict__ Xc,
                                             unsigned short* __restrict__ Wt,
                                             float* __restrict__ pS,
                                             float* __restrict__ pC0,
                                             float* __restrict__ pC1) {
  __shared__ __align__(16) unsigned char smem[36864];
  const int t = threadIdx.x;
  const int bx = blockIdx.x;

  if (bx >= 4096) {
    // ---- convert_w: w [co][ci][3][3] fp32 -> Wt2 [tap][ci_oct][co][8] bf16
    unsigned short* lw = (unsigned short*)smem;  // [cl][ci][tap]
    const int co0 = (bx - 4096) << 3;
    const float* src = w + co0 * 2304;
    for (int k = t; k < 18432; k += 256) lw[k] = f2bf(src[k]);  // coalesced
    __syncthreads();
    for (int g = t; g < 18432; g += 256) {
      const int tap = g >> 11, rem = g & 2047;
      const int o = rem >> 6, rem2 = rem & 63;
      const int cl = rem2 >> 3, e = rem2 & 7;
      Wt[(((tap << 5) + o) << 11) + ((co0 + cl) << 3) + e] =
          lw[cl * 2304 + ((o << 3) + e) * 9 + tap];
    }
    return;
  }

  // ---- transpose_x: x [b][c][h][w] fp32 -> Xc2 [b][h][ci_oct][w][8] bf16,
  // plus per-(b,h) pool partials (no atomics)
  float (*tile)[130] = (float(*)[130])smem;
  const int bh = bx >> 2;              // 0..1023 = b*128 + h
  const int b = bh >> 7;
  const int c0 = (bx & 3) << 6;        // 0,64,128,192
  const float* xp = x + ((b * CC) * HH + (bh & 127)) * WW;
#pragma unroll
  for (int i = 0; i < 8; ++i) {
    int idx = t + (i << 8);            // 0..2047
    int cr = idx >> 5, wq = idx & 31;  // 32 float4 per 128-wide row
    float4 v = *(const float4*)(xp + (c0 + cr) * (HH * WW) + (wq << 2));
    tile[cr][(wq << 2) + 0] = v.x;
    tile[cr][(wq << 2) + 1] = v.y;
    tile[cr][(wq << 2) + 2] = v.z;
    tile[cr][(wq << 2) + 3] = v.w;
  }
  __syncthreads();
  const int ob = c0 >> 3;
#pragma unroll
  for (int i = 0; i < 4; ++i) {
    int g = t + (i << 8);              // 0..1023
    int o = g >> 7, wr = g & 127;
    bf16x8 v;
#pragma unroll
    for (int e = 0; e < 8; ++e) v[e] = (short)f2bf(tile[(o << 3) + e][wr]);
    *(bf16x8*)(Xc + ((bh * 32) + ob + o) * 1024 + wr * 8) = v;
  }
  {
    const int c = t >> 2, seg = t & 3;
    float s = 0.f;
#pragma unroll
    for (int k = 0; k < 32; ++k)
      s += tile[c][(seg << 5) + ((k + (seg << 3)) & 31)];  // bank-phase rotate
    s += __shfl_xor(s, 1);
    s += __shfl_xor(s, 2);
    if (seg == 0) {
      const int idx = (bh << 8) + c0 + c;
      pS[idx]  = s;
      pC0[idx] = tile[c][0];
      pC1[idx] = tile[c][127];
    }
  }
}

// ---------------------------------------------------------------------------
// Kernel 2: p[b][co] = bd[co] + (1/16384) * sum_k w[co][k] * ts[b][k].
// Unchanged from round 5.
// ---------------------------------------------------------------------------
__global__ __launch_bounds__(256) void k_pool2(const float* __restrict__ w,
                                               const float* __restrict__ bd,
                                               const float* __restrict__ pS,
                                               const float* __restrict__ pC0,
                                               const float* __restrict__ pC1,
                                               float* __restrict__ p_buf) {
  __shared__ float ts[2304];   // flat [ci*9 + tap]
  const int b = blockIdx.y, t = threadIdx.x;
  const int lane = t & 63, wid = t >> 6;
  {
    const int base = (b << 15) + t;          // b*128*256 + ci
    float S = 0.f, C0 = 0.f, C1 = 0.f;
#pragma unroll 4
    for (int h = 0; h < 128; ++h) {
      S  += pS [base + (h << 8)];
      C0 += pC0[base + (h << 8)];
      C1 += pC1[base + (h << 8)];
    }
    const float R0 = pS[base],  R1 = pS[base + (127 << 8)];
    const float x00 = pC0[base], xH0 = pC0[base + (127 << 8)];
    const float x0W = pC1[base], xHW = pC1[base + (127 << 8)];
    const float er[3] = {R1, 0.f, R0};
    const float ec[3] = {C1, 0.f, C0};
    const float cor[9] = {xHW, 0.f, xH0, 0.f, 0.f, 0.f, x0W, 0.f, x00};
#pragma unroll
    for (int kh = 0; kh < 3; ++kh)
#pragma unroll
      for (int kw = 0; kw < 3; ++kw)
        ts[t * 9 + kh * 3 + kw] = S - er[kh] - ec[kw] + cor[kh * 3 + kw];
  }
  __syncthreads();
  float4 tv[9];
#pragma unroll
  for (int q = 0; q < 9; ++q) tv[q] = *(const float4*)&ts[(q * 64 + lane) * 4];
  const int co = (blockIdx.x << 3) + (wid << 1);
#pragma unroll
  for (int c2 = 0; c2 < 2; ++c2) {
    const float4* wr = (const float4*)(w + (co + c2) * 2304) + lane;
    float s = 0.f;
#pragma unroll
    for (int q = 0; q < 9; ++q) {
      float4 wv = wr[q * 64];
      s += wv.x * tv[q].x + wv.y * tv[q].y + wv.z * tv[q].z + wv.w * tv[q].w;
    }
    s += __shfl_xor(s, 1);  s += __shfl_xor(s, 2);  s += __shfl_xor(s, 4);
    s += __shfl_xor(s, 8);  s += __shfl_xor(s, 16); s += __shfl_xor(s, 32);
    if (lane == 0) p_buf[(b << 8) + co + c2] = bd[co + c2] + s * (1.0f / 16384.0f);
  }
}

// ---------------------------------------------------------------------------
// Kernel 3 v7: implicit-GEMM conv + fused SE MLP prologue.
// v7 = EXACT v5 K-loop (stage at loop-top; 116.6 us, no spill) + the v6 SE
// prologue. v6's stage@s==8 put 16 address computations in the MFMA-live
// region -> spill (+281 MB scratch writes). Lesson kept: the K-loop has
// ~30 registers of headroom; no new live values inside it.
// ---------------------------------------------------------------------------
__global__ __launch_bounds__(256, 2) void k_conv(
    const unsigned short* __restrict__ Xc, const unsigned short* __restrict__ Wt,
    const float* __restrict__ bias, const float* __restrict__ p_buf,
    const float* __restrict__ w1, const float* __restrict__ b1,
    const float* __restrict__ w2, const float* __restrict__ b2,
    float* __restrict__ out) {
  // dynamic LDS: Xs [buf:2][dh:4][oct:4][wp:130][8] bf16 = 66560 B,
  // then p_lds[256] + h1[64] + sc[128] floats = 1792 B. Total 68352 B.
  extern __shared__ __align__(16) unsigned short Xs[];
  float* p_lds = (float*)(Xs + 33280);
  float* h1s   = p_lds + 256;
  float* sc    = h1s + 64;
  const int t = threadIdx.x;
  const int lin = (blockIdx.y << 1) | blockIdx.x;   // 0..1023
  const int Wk = ((lin & 7) << 7) | (lin >> 3);     // XCD swizzle: XCD k -> b=k
  const int m0 = (Wk & 1) << 7;
  const int bhp = Wk >> 1;                          // 0..511
  const int b = bhp >> 6;
  const int h0 = (bhp & 63) << 1;                   // even row; block does h0,h0+1
  const int lane = t & 63, wid = t >> 6;
  const int wave_m = (wid & 1) << 6, wave_n = (wid >> 1) << 6;
  const int n0 = lane & 15, quad = lane >> 4;
  const int part = wid & 1, rsel = wid >> 1;

  bf16x8 z8 = {0, 0, 0, 0, 0, 0, 0, 0};
  // zero halo columns wp=0 and wp=129 (both buffers), once
  if (t < 64) {
    int bi = t >> 5, rem = t & 31;
    int dh = rem >> 3, rem2 = rem & 7, q = rem2 >> 1, side = rem2 & 1;
    *(bf16x8*)&Xs[bi * 16640 + dh * 4160 + q * 1040 + (side ? 1032 : 0)] = z8;
  }
  // out-of-image rows stay zero (staging skips them)
  if (h0 == 0 || h0 == 126) {
    const int dhz = (h0 == 0) ? 0 : 3;
    for (int g = t; g < 1040; g += 256) {
      int bi = g >= 520, gg = g - bi * 520;
      *(bf16x8*)&Xs[bi * 16640 + dhz * 4160 + gg * 8] = z8;
    }
  }

  auto stage = [&](int cb8, int bi) {
    const int ob = cb8 << 2;
#pragma unroll
    for (int r = 0; r < 8; ++r) {
      const int rr = (r << 1) | rsel;      // 16 regions of 2 KB: (dh, octet)
      const int dh = rr >> 2, q = rr & 3;
      const int hh = h0 - 1 + dh;
      if (hh >= 0 && hh < HH) {
        const unsigned short* gp =
            Xc + ((((b << 7) + hh) * 32 + ob + q) << 10) + (part << 9) + (lane << 3);
        unsigned short* lp =
            &Xs[bi * 16640 + dh * 4160 + q * 1040 + 8 + (part << 9) + (lane << 3)];
        async16(gp, lp);
      }
    }
  };

  f32x4 acc[2][4][4];
  f32x4 zero4 = {0.f, 0.f, 0.f, 0.f};
#pragma unroll
  for (int r = 0; r < 2; ++r)
#pragma unroll
    for (int i = 0; i < 4; ++i)
#pragma unroll
      for (int j = 0; j < 4; ++j) acc[r][i][j] = zero4;

  stage(0, 0);

  // ---- fused SE MLP (overlaps stage(0) latency); identical math to k_se2
  p_lds[t] = p_buf[(b << 8) + t];
  __syncthreads();
  {
    const float4 pv = *(const float4*)&p_lds[lane << 2];
#pragma unroll
    for (int i = 0; i < 16; ++i) {
      const int r = (wid << 4) + i;
      float4 wv = ((const float4*)(w1 + (r << 8)))[lane];
      float s = wv.x * pv.x + wv.y * pv.y + wv.z * pv.z + wv.w * pv.w;
      s += __shfl_xor(s, 1);  s += __shfl_xor(s, 2);  s += __shfl_xor(s, 4);
      s += __shfl_xor(s, 8);  s += __shfl_xor(s, 16); s += __shfl_xor(s, 32);
      if (lane == 0) {
        float v = b1[r] + s;
        h1s[r] = v > 0.f ? v : 0.f;
      }
    }
  }
  __syncthreads();
  if (t < 128) {
    float s2 = b2[m0 + t];
    const float* wr2 = w2 + ((m0 + t) << 6);
#pragma unroll
    for (int k = 0; k < 64; ++k) s2 += wr2[k] * h1s[k];
    sc[t] = 1.0f / (1.0f + expf(-s2));
  }
  __syncthreads();

  for (int cb8 = 0; cb8 < 8; ++cb8) {
    const int cur = cb8 & 1;
    if (cb8 < 7) stage(cb8 + 1, cur ^ 1);   // v5 placement: loop-top
    // A base: Wt2[tap][(cb8*4)+quad][co][8]; B base in current Xs buffer
    const unsigned short* wb =
        Wt + ((((cb8 << 2) + quad) << 8) + m0 + wave_m + n0) * 8;
    const unsigned short* xb = &Xs[cur * 16640 + quad * 1040 + (wave_n + n0) * 8];

    // A plane p = kw*3+kh -> Wt tap = kh*3+kw = (p%3)*3 + p/3 ; slot p%3.
    bf16x8 af[3][4], bg[2][4];
#pragma unroll
    for (int i = 0; i < 4; ++i) af[0][i] = *(const bf16x8*)(wb + 0 * 65536 + i * 128);
#pragma unroll
    for (int i = 0; i < 4; ++i) af[1][i] = *(const bf16x8*)(wb + 3 * 65536 + i * 128);
#pragma unroll
    for (int j = 0; j < 4; ++j) bg[0][j] = *(const bf16x8*)(xb + (j << 4) * 8);

#pragma unroll
    for (int kw = 0; kw < 3; ++kw) {
#pragma unroll
      for (int dh = 0; dh < 4; ++dh) {
        const int s = (kw << 2) + dh;          // 12 steps per cb8
        if (s < 11) {                           // B prefetch, 1 step ahead
          const int sn = s + 1, kwn = sn >> 2, dhn = sn & 3;
#pragma unroll
          for (int j = 0; j < 4; ++j)
            bg[sn & 1][j] =
                *(const bf16x8*)(xb + dhn * 4160 + (((j << 4) + kwn)) * 8);
        }
        __builtin_amdgcn_s_setprio(1);
        if (dh >= 1) {                          // row1: plane p1 = kw*3+dh-1
          const int p1 = kw * 3 + dh - 1;
#pragma unroll
          for (int i = 0; i < 4; ++i)
#pragma unroll
            for (int j = 0; j < 4; ++j)
              acc[1][i][j] = __builtin_amdgcn_mfma_f32_16x16x32_bf16(
                  af[p1 % 3][i], bg[s & 1][j], acc[1][i][j], 0, 0, 0);
        }
        if (dh <= 2) {                          // row0: plane p0 = kw*3+dh
          const int p0 = kw * 3 + dh;
#pragma unroll
          for (int i = 0; i < 4; ++i)
#pragma unroll
            for (int j = 0; j < 4; ++j)
              acc[0][i][j] = __builtin_amdgcn_mfma_f32_16x16x32_bf16(
                  af[p0 % 3][i], bg[s & 1][j], acc[0][i][j], 0, 0, 0);
        }
        __builtin_amdgcn_s_setprio(0);
        if (s >= 1 && s <= 7) {                 // A prefetch: plane s+1
          const int pn = s + 1;                  // tap = (pn%3)*3 + pn/3
          const int tapn = (pn % 3) * 3 + pn / 3;
#pragma unroll
          for (int i = 0; i < 4; ++i)
            af[pn % 3][i] = *(const bf16x8*)(wb + tapn * 65536 + i * 128);
        }
      }
    }
    __syncthreads();
  }

  // epilogue: D col = lane&15 (w), row = quad*4+reg (co); y = (acc+bias)*scale
#pragma unroll
  for (int i = 0; i < 4; ++i) {
    const int mloc = wave_m + (i << 4) + (quad << 2);  // 0..127 within block
    const int mrow = m0 + mloc;
    float bs[4], ss[4];
#pragma unroll
    for (int r4 = 0; r4 < 4; ++r4) {
      bs[r4] = bias[mrow + r4];
      ss[r4] = sc[mloc + r4];
    }
#pragma unroll
    for (int r = 0; r < 2; ++r)
#pragma unroll
      for (int j = 0; j < 4; ++j) {
        const int wcol = wave_n + (j << 4) + n0;
        float* op = out + ((((b << 8) + mrow) * HH) + h0 + r) * WW + wcol;
#pragma unroll
        for (int r4 = 0; r4 < 4; ++r4)
          op[r4 * (HH * WW)] = (acc[r][i][j][r4] + bs[r4]) * ss[r4];
      }
  }
}

extern "C" void kernel_launch(void* const* d_in, const int* in_sizes, int n_in,
                              void* d_out, int out_size, void* d_ws, size_t ws_size,
                              hipStream_t stream) {
  const float* x  = (const float*)d_in[0];
  const float* wd = (const float*)d_in[1];
  const float* bd = (const float*)d_in[2];
  const float* w1 = (const float*)d_in[3];
  const float* b1 = (const float*)d_in[4];
  const float* w2 = (const float*)d_in[5];
  const float* b2 = (const float*)d_in[6];
  float* out = (float*)d_out;

  // workspace layout
  char* ws = (char*)d_ws;
  unsigned short* Xc = (unsigned short*)ws;                     // 67108864 B
  unsigned short* Wt = (unsigned short*)(ws + 67108864);        //  1179648 B
  float* p_buf = (float*)(ws + 68362240);                       //     8192 B

  // per-(b,h) pool partials live in d_out scratch (dead until k_conv writes):
  // pS/pC0/pC1 each 8*128*256 floats = 1 MB
  float* pS  = out;
  float* pC0 = out + 262144;
  float* pC1 = out + 524288;

  // k_conv uses 68,352 B dynamic LDS (> 64 KB static limit)
  (void)hipFuncSetAttribute((const void*)k_conv,
                            hipFuncAttributeMaxDynamicSharedMemorySize, 68352);

  k_pre<<<dim3(4128), dim3(256), 0, stream>>>(x, wd, Xc, Wt, pS, pC0, pC1);
  k_pool2<<<dim3(32, 8), dim3(256), 0, stream>>>(wd, bd, pS, pC0, pC1, p_buf);
  k_conv<<<dim3(2, 512), dim3(256), 68352, stream>>>(Xc, Wt, bd, p_buf,
                                                     w1, b1, w2, b2, out);
}